// Round 5
// baseline (218.370 us; speedup 1.0000x reference)
//
#include <hip/hip_runtime.h>
#include <math.h>

// Problem constants (fixed by reference setup_inputs)
#define S      2048
#define DK     64
#define NBH    32            // B*H
#define QW     32            // q rows per WAVE (2 A-fragment pairs)
#define QBLK   128           // q rows per block (4 waves)
#define NQG    (S / QBLK)    // 16 q-groups per bh
#define NBLK   (NBH * NQG)   // 512 blocks
#define NTHR   256
#define NST    (S / 16)      // 128 k-steps of 16 rows

typedef __bf16 bf16x8 __attribute__((ext_vector_type(8)));
typedef float  f32x4  __attribute__((ext_vector_type(4)));
typedef float  f32x8  __attribute__((ext_vector_type(8)));

#if __has_builtin(__builtin_amdgcn_exp2f)
#define EXP2F(x) __builtin_amdgcn_exp2f(x)
#else
#define EXP2F(x) exp2f(x)
#endif

__device__ __forceinline__ float gelu_exact(float x) {
    return 0.5f * x * (1.0f + erff(x * 0.70710678118654752f));
}

// ---------------------------------------------------------------------------
// Fused attention-stats + MLP head — BARRIER-FREE main loop.
// Post-mortem r1/r3/r4: every barrier-synced LDS pipeline lands 100-115 us
// with all pipes <21% busy (~3800 exposed cyc/chunk). Fix: make waves fully
// independent. Each wave owns 32 q-rows (2 A-frag pairs, Q pre-scaled by
// (1/8)*log2e) and sweeps the FULL k-range in 128 steps of 16 K-rows,
// loading its B-fragment straight from global (the block's 4 waves read the
// SAME K stream -> L1 reuse; per-bh K = 512 KB, L2-resident, XCD-pinned via
// bh-major grid: r3/r4 measured FETCH 74->16.5 MB). 2-deep register
// prefetch with parity-NAMED slots (A=even, B=odd steps — no runtime-indexed
// arrays, rule #20). NO LDS, NO barriers, NO waitcnt asm in the loop.
// Per step: 4x mfma_f32_16x16x32_bf16 + per-row no-max stats in the log2
// domain (m, Z=sum 2^s', Z2=sum 2^2s', sm=sum s'; sum/max restored by *ln2;
// Z/Z2/var are domain-invariant). exp2 never overflows (|s'| <~ 9).
// __launch_bounds__(256,4): VGPR<=128 (main loop needs ~110; r3/r4's 256-VGPR
// balloon halved residency). Last block (atomic counter) runs the MLP head.
// ---------------------------------------------------------------------------
__global__ __launch_bounds__(NTHR, 4) void fused_attn_stats_mlp(
    const float* __restrict__ Q, const float* __restrict__ K,
    const float* __restrict__ W1, const float* __restrict__ b1,
    const float* __restrict__ W2, const float* __restrict__ b2,
    const float* __restrict__ W3, const float* __restrict__ b3,
    float* __restrict__ ws, float* __restrict__ out)
{
    __shared__ float headLds[32 * 65 + 96 + 32];   // H1 | feat | logt (head only)
    __shared__ float red[3];
    __shared__ int lastF;

    const int t    = threadIdx.x;
    const int lane = t & 63;
    const int w    = t >> 6;        // wave 0..3 -> q rows [qg*128 + 32w, +32)
    const int lrow = lane & 15;     // fragment row (A: q-row, B: k-row)
    const int lq   = lane >> 4;     // quad: d = lq*8 + j
    const int bh   = blockIdx.x;
    const int qg   = blockIdx.y;

    // ---- A fragments (once, from global; scaled by log2e/8) ----
    const float SC = 0.18033688011112042592f;      // (1/sqrt(64)) * log2(e)
    const float* qbase = Q + ((size_t)bh * S + (size_t)qg * QBLK + w * QW + lrow) * DK;
    f32x8 qa = *(const f32x8*)(qbase + lq * 8);
    f32x8 qb = *(const f32x8*)(qbase + 32 + lq * 8);
    f32x8 qc = *(const f32x8*)(qbase + 16 * DK + lq * 8);
    f32x8 qd = *(const f32x8*)(qbase + 16 * DK + 32 + lq * 8);
    const bf16x8 a0_lo = __builtin_convertvector(qa * SC, bf16x8);
    const bf16x8 a0_hi = __builtin_convertvector(qb * SC, bf16x8);
    const bf16x8 a1_lo = __builtin_convertvector(qc * SC, bf16x8);
    const bf16x8 a1_hi = __builtin_convertvector(qd * SC, bf16x8);

    if (t < 3) red[t] = 0.0f;
    __syncthreads();                // red[] init visible; only barrier pre-epilogue

    // ---- B pointer: lane reads K[step*16 + lrow][lq*8 .. +8) and +32 ----
    const float* kb = K + (size_t)bh * S * DK + (size_t)lrow * DK + lq * 8;

    // per-row stats; index u = f*4+i -> q-row w*32 + f*16 + lq*4 + i
    float m[8], Zs[8], Z2[8], sm[8];
#pragma unroll
    for (int u = 0; u < 8; ++u) { m[u] = -INFINITY; Zs[u] = 0.f; Z2[u] = 0.f; sm[u] = 0.f; }

    // ---- 2-deep prefetch, parity-named slots ----
    f32x8 loA = *(const f32x8*)(kb);
    f32x8 hiA = *(const f32x8*)(kb + 32);
    f32x8 loB = *(const f32x8*)(kb + 1024);
    f32x8 hiB = *(const f32x8*)(kb + 1024 + 32);

#define STEP(LO, HI, JN) {                                              \
        const bf16x8 _blo = __builtin_convertvector(LO, bf16x8);        \
        const bf16x8 _bhi = __builtin_convertvector(HI, bf16x8);        \
        const float* _np = kb + (size_t)(JN) * 1024;                    \
        LO = *(const f32x8*)(_np);                                      \
        HI = *(const f32x8*)(_np + 32);                                 \
        f32x4 _ac0 = {0.f, 0.f, 0.f, 0.f};                              \
        f32x4 _ac1 = {0.f, 0.f, 0.f, 0.f};                              \
        _ac0 = __builtin_amdgcn_mfma_f32_16x16x32_bf16(a0_lo, _blo, _ac0, 0, 0, 0); \
        _ac0 = __builtin_amdgcn_mfma_f32_16x16x32_bf16(a0_hi, _bhi, _ac0, 0, 0, 0); \
        _ac1 = __builtin_amdgcn_mfma_f32_16x16x32_bf16(a1_lo, _blo, _ac1, 0, 0, 0); \
        _ac1 = __builtin_amdgcn_mfma_f32_16x16x32_bf16(a1_hi, _bhi, _ac1, 0, 0, 0); \
        _Pragma("unroll")                                               \
        for (int i = 0; i < 4; ++i) {                                   \
            const float s0 = _ac0[i], s1 = _ac1[i];                     \
            const float p0 = EXP2F(s0), p1 = EXP2F(s1);                 \
            m[i]      = fmaxf(m[i], s0);    m[4 + i]  = fmaxf(m[4 + i], s1); \
            Zs[i]    += p0;                 Zs[4 + i] += p1;            \
            Z2[i]     = fmaf(p0, p0, Z2[i]);                            \
            Z2[4 + i] = fmaf(p1, p1, Z2[4 + i]);                        \
            sm[i]    += s0;                 sm[4 + i] += s1;            \
        } }

    for (int j = 0; j < NST; j += 2) {
        const int j2 = (j + 2 < NST) ? j + 2 : NST - 1;   // clamped reloads
        const int j3 = (j + 3 < NST) ? j + 3 : NST - 1;   // are never consumed
        STEP(loA, hiA, j2);       // even step j
        STEP(loB, hiB, j3);       // odd step j+1
    }

    // ---- reduce across the 16 k-column lanes sharing each q-row ----
#pragma unroll
    for (int off = 1; off < 16; off <<= 1) {
#pragma unroll
        for (int u = 0; u < 8; ++u) {
            m[u]   = fmaxf(m[u], __shfl_xor(m[u], off, 64));
            Zs[u] += __shfl_xor(Zs[u], off, 64);
            Z2[u] += __shfl_xor(Z2[u], off, 64);
            sm[u] += __shfl_xor(sm[u], off, 64);
        }
    }
    if (lrow == 0) {
        const float LN2 = 0.69314718055994530942f;
        float psum = 0.f, pmax = 0.f, pvar = 0.f;
#pragma unroll
        for (int u = 0; u < 8; ++u) {
            psum += sm[u];
            pmax += m[u];
            const float iz = 1.0f / Zs[u];
            // var(probs, ddof=1) = (Z2/Z^2 - 1/n)/(n-1); scale-invariant
            pvar += (Z2[u] * iz * iz - (1.0f / 2048.0f)) * (1.0f / 2047.0f);
        }
        atomicAdd(&red[0], psum * LN2);     // back to natural-log domain
        atomicAdd(&red[1], pmax * LN2);
        atomicAdd(&red[2], pvar);
    }
    __syncthreads();
    if (t == 0) {
        atomicAdd(&ws[bh * 3 + 0], red[0]);
        atomicAdd(&ws[bh * 3 + 1], red[1]);
        atomicAdd(&ws[bh * 3 + 2], red[2]);
        __threadfence();
        const int old = atomicAdd((int*)(ws + 96), 1);
        lastF = (old == NBLK - 1);
    }
    __syncthreads();
    if (!lastF) return;

    // =========================== MLP head (last block) ======================
    float* H1    = headLds;             // 32*65 floats
    float* featL = headLds + 32 * 65;   // 96 floats
    float* logtL = featL + 96;          // 32 floats

    if (t < 96)               featL[t] = atomicAdd(&ws[t], 0.0f); // coherent read
    if (t >= 96 && t < 128)   logtL[t - 96] = 0.0f;
    __syncthreads();

    if (t < 64) {
        const float w1a = W1[t], w1b = W1[64 + t], w1c = W1[128 + t], bb1 = b1[t];
        for (int b = 0; b < 32; ++b) {
            const float f0 = featL[b * 3 + 0] * (1.0f / ((float)S * (float)S));
            const float f1 = featL[b * 3 + 1] * (1.0f / (float)S);
            const float f2 = featL[b * 3 + 2] * (1.0f / (float)S);
            H1[b * 65 + t] = gelu_exact(f0 * w1a + f1 * w1b + f2 * w1c + bb1);
        }
    }
    __syncthreads();
    {
        // 256 threads: 8 threads per bh, 8 hidden-2 units each
        const int b = t >> 3, jb = (t & 7) * 8;
        float acc[8];
#pragma unroll
        for (int u = 0; u < 8; ++u) acc[u] = 0.0f;
#pragma unroll 4
        for (int k = 0; k < 64; ++k) {
            const float hk = H1[b * 65 + k];
            const float4 wa = *(const float4*)&W2[k * 64 + jb];
            const float4 wb = *(const float4*)&W2[k * 64 + jb + 4];
            acc[0] += hk * wa.x; acc[1] += hk * wa.y;
            acc[2] += hk * wa.z; acc[3] += hk * wa.w;
            acc[4] += hk * wb.x; acc[5] += hk * wb.y;
            acc[6] += hk * wb.z; acc[7] += hk * wb.w;
        }
        float part = 0.0f;
#pragma unroll
        for (int u = 0; u < 8; ++u)
            part += gelu_exact(acc[u] + b2[jb + u]) * W3[jb + u];
        atomicAdd(&logtL[b], part);
    }
    __syncthreads();
    if (t < 32) {
        float lt = logtL[t] + b3[0];
        lt = fminf(fmaxf(lt, -2.3025850929940457f), 2.3025850929940457f);
        out[t] = expf(lt);
    }
}

// ---------------------------------------------------------------------------
extern "C" void kernel_launch(void* const* d_in, const int* in_sizes, int n_in,
                              void* d_out, int out_size, void* d_ws, size_t ws_size,
                              hipStream_t stream)
{
    const float* Q  = (const float*)d_in[0];
    const float* K  = (const float*)d_in[1];
    const float* W1 = (const float*)d_in[2];
    const float* b1 = (const float*)d_in[3];
    const float* W2 = (const float*)d_in[4];
    const float* b2 = (const float*)d_in[5];
    const float* W3 = (const float*)d_in[6];
    const float* b3 = (const float*)d_in[7];
    float* out = (float*)d_out;
    float* ws  = (float*)d_ws;

    // zero the 96 stat accumulators + the int block counter at ws[96]
    hipMemsetAsync(ws, 0, 512, stream);

    dim3 grid(NBH, NQG);   // bh fastest -> each bh's K pinned to one XCD L2
    fused_attn_stats_mlp<<<grid, NTHR, 0, stream>>>(Q, K, W1, b1, W2, b2, W3, b3, ws, out);
}